// Round 21
// baseline (116.382 us; speedup 1.0000x reference)
//
#include <hip/hip_runtime.h>
#include <stdint.h>

#define B_  2
#define L_  2048
#define HD_ 1024
#define H_  16
#define D_  64

typedef unsigned short u16;
typedef __attribute__((ext_vector_type(8))) short bf16x8;
typedef __attribute__((ext_vector_type(4))) float f32x4;

#define MFMA16(a, b, c) __builtin_amdgcn_mfma_f32_16x16x32_bf16((a), (b), (c), 0, 0, 0)

__device__ __forceinline__ void gload16(const void* g, void* l) {
  __builtin_amdgcn_global_load_lds((const __attribute__((address_space(1))) void*)g,
                                   (__attribute__((address_space(3))) void*)l, 16, 0, 0);
}

__device__ __forceinline__ u16 f2bf(float f) {
  union { float f; uint32_t u; } c; c.f = f;
  uint32_t u = c.u + 0x7FFFu + ((c.u >> 16) & 1u);
  return (u16)(u >> 16);
}

__device__ __forceinline__ float bf2f(u16 v) {
  union { uint32_t u; float f; } c; c.u = (uint32_t)v << 16;
  return c.f;
}

__device__ __forceinline__ uint32_t cvt_pk_bf16(float lo, float hi) {
  uint32_t r;
  asm("v_cvt_pk_bf16_f32 %0, %1, %2" : "=v"(r) : "v"(lo), "v"(hi));
  return r;
}

// ---------------- fused prologue: cast x,y -> bf16 AND transpose+cast 3 weights ----
// blocks 0..4095: cast. blocks 4096..5119: 64x64 transpose tiles, float4 reads +
// ushort4 writes (vs old 32x32 scalar): Wq 256 tiles, Wkv 512, Wp 256.
__global__ void prologue_k(const float* __restrict__ x, const float* __restrict__ y,
                           u16* __restrict__ xb, u16* __restrict__ yb,
                           const float* __restrict__ Wq, const float* __restrict__ Wkv,
                           const float* __restrict__ Wp,
                           u16* __restrict__ Wqt, u16* __restrict__ Wkvt,
                           u16* __restrict__ Wpt) {
  int bid = blockIdx.x;
  int t = threadIdx.x;
  if (bid < 4096) {
    const float* in = bid < 2048 ? x : y;
    u16* out = bid < 2048 ? xb : yb;
    int i = ((bid & 2047) * 256 + t) * 8;   // 2048*256*8 == 4M exact
    float4 a = *(const float4*)(in + i);
    float4 b = *(const float4*)(in + i + 4);
    bf16x8 r;
    r[0] = (short)f2bf(a.x); r[1] = (short)f2bf(a.y); r[2] = (short)f2bf(a.z); r[3] = (short)f2bf(a.w);
    r[4] = (short)f2bf(b.x); r[5] = (short)f2bf(b.y); r[6] = (short)f2bf(b.z); r[7] = (short)f2bf(b.w);
    *(bf16x8*)(out + i) = r;
    return;                                 // block-uniform, before any barrier
  }
  int f = bid - 4096;
  const float* src; u16* dst; int Nfull, bx, by;
  if (f < 256)      { src = Wq;  dst = Wqt;  Nfull = 1024; bx = f & 15;  by = f >> 4; }
  else if (f < 768) { int g2 = f - 256; src = Wkv; dst = Wkvt; Nfull = 2048; bx = g2 & 31; by = g2 >> 5; }
  else              { int g2 = f - 768; src = Wp;  dst = Wpt;  Nfull = 1024; bx = g2 & 15; by = g2 >> 4; }
  __shared__ float tile[64][65];
  int c = t & 15, r = t >> 4;               // c: 16 float4 cols, r: 16 rows/pass
  int nb = bx * 64, kb = by * 64;
#pragma unroll
  for (int i = 0; i < 4; i++) {
    float4 v = *(const float4*)(src + (size_t)(kb + r + i * 16) * Nfull + nb + c * 4);
    tile[r + i * 16][c * 4 + 0] = v.x;
    tile[r + i * 16][c * 4 + 1] = v.y;
    tile[r + i * 16][c * 4 + 2] = v.z;
    tile[r + i * 16][c * 4 + 3] = v.w;
  }
  __syncthreads();
#pragma unroll
  for (int i = 0; i < 4; i++) {
    int nl = r + i * 16;                    // dst row = n index within tile
    ushort4 o;
    o.x = f2bf(tile[c * 4 + 0][nl]);
    o.y = f2bf(tile[c * 4 + 1][nl]);
    o.z = f2bf(tile[c * 4 + 2][nl]);
    o.w = f2bf(tile[c * 4 + 3][nl]);
    *(ushort4*)(dst + (size_t)(nb + nl) * 1024 + kb + c * 4) = o;
  }
}

// ---------------- 64-row GEMM body (proven R19) --------------
__device__ __forceinline__ void gemm64_body(
    char* sA, char* sB,                 // sA 2*8192, sB 2*16384
    const u16* __restrict__ A, const u16* __restrict__ Bt,
    const float* __restrict__ bias, void* __restrict__ outp,
    int N, int epi, int bm, int bn)
{
  int t = threadIdx.x;
  int lane = t & 63, w = t >> 6;
  int g = lane >> 4, l15 = lane & 15;
  int wr = w >> 1, wc = w & 1;

  f32x4 zero = {0.f, 0.f, 0.f, 0.f};
  f32x4 acc[2][4];
#pragma unroll
  for (int mi = 0; mi < 2; mi++)
#pragma unroll
    for (int ni = 0; ni < 4; ni++) acc[mi][ni] = zero;

#define GSTAGE64(bufi, k0s) do {                                                        \
    _Pragma("unroll")                                                                   \
    for (int it = 0; it < 2; it++) {      /* A: 512 chunks (64 rows x 8 slots) */       \
      int c = it * 256 + t;                                                             \
      int r = c >> 3, sp = c & 7;                                                       \
      int off = (sp ^ (r & 7)) << 4;                                                    \
      gload16((const char*)(A + (size_t)(bm + r) * 1024 + (k0s)) + off,                 \
              sA + (bufi) * 8192 + c * 16);                                             \
    }                                                                                   \
    _Pragma("unroll")                                                                   \
    for (int it = 0; it < 4; it++) {      /* B: 1024 chunks (128 rows x 8 slots) */     \
      int c = it * 256 + t;                                                             \
      int r = c >> 3, sp = c & 7;                                                       \
      int off = (sp ^ (r & 7)) << 4;                                                    \
      gload16((const char*)(Bt + (size_t)(bn + r) * 1024 + (k0s)) + off,                \
              sB + (bufi) * 16384 + c * 16);                                            \
    } } while (0)

  GSTAGE64(0, 0);
  int buf = 0;
#pragma unroll 1
  for (int kt = 0; kt < 16; kt++) {
    __builtin_amdgcn_sched_barrier(0);
    __builtin_amdgcn_s_barrier();                      // B1: buf^1 free to overwrite
    if (kt < 15) {
      GSTAGE64(buf ^ 1, (kt + 1) << 6);                // next tile's 6 loads in flight
      asm volatile("s_waitcnt vmcnt(6)" ::: "memory"); // own tile's batch landed
    } else {
      asm volatile("s_waitcnt vmcnt(0)" ::: "memory"); // last tile: full drain
    }
    __builtin_amdgcn_s_barrier();                      // B2: tile kt resident block-wide
    __builtin_amdgcn_sched_barrier(0);

    const char* cA = sA + buf * 8192;
    const char* cB = sB + buf * 16384;
#pragma unroll
    for (int kc = 0; kc < 2; kc++) {
      bf16x8 af[2], bfr[4];
#pragma unroll
      for (int mi = 0; mi < 2; mi++) {
        int r = wr * 32 + mi * 16 + l15;
        af[mi] = *(const bf16x8*)(cA + r * 128 + (((kc * 4 + g) ^ (r & 7)) << 4));
      }
#pragma unroll
      for (int ni = 0; ni < 4; ni++) {
        int r = wc * 64 + ni * 16 + l15;
        bfr[ni] = *(const bf16x8*)(cB + r * 128 + (((kc * 4 + g) ^ (r & 7)) << 4));
      }
#pragma unroll
      for (int mi = 0; mi < 2; mi++)
#pragma unroll
        for (int ni = 0; ni < 4; ni++)
          acc[mi][ni] = MFMA16(af[mi], bfr[ni], acc[mi][ni]);
    }
    buf ^= 1;
  }
#undef GSTAGE64

  float bv[4];
#pragma unroll
  for (int ni = 0; ni < 4; ni++) bv[ni] = bias[bn + wc * 64 + ni * 16 + l15];

  if (epi == 2) {
    float* fo = (float*)outp;
#pragma unroll
    for (int mi = 0; mi < 2; mi++)
#pragma unroll
      for (int ni = 0; ni < 4; ni++) {
        int n = bn + wc * 64 + ni * 16 + l15;
#pragma unroll
        for (int r = 0; r < 4; r++) {
          int m = bm + wr * 32 + mi * 16 + g * 4 + r;
          fo[(size_t)m * N + n] = acc[mi][ni][r] + bv[ni];
        }
      }
  } else {
    const float QS = (epi == 0) ? 0.125f * 1.44269504089f : 1.0f;  // fold attn scale into Q
    u16* ob = (u16*)outp;
#pragma unroll
    for (int mi = 0; mi < 2; mi++)
#pragma unroll
      for (int ni = 0; ni < 4; ni++) {
        int n = bn + wc * 64 + ni * 16 + l15;
        int kv = n >> 10;          // 0 for epi0 (N=1024)
        int hh = (n >> 6) & 15;
        int dd = n & 63;
        int m0 = bm + wr * 32 + mi * 16 + g * 4;
        int bb = m0 >> 11, lq0 = m0 & 2047;
        if (epi == 1 && kv == 1) {
          // V stored TRANSPOSED: [b,h,d,l]; r -> lq consecutive -> one 8B store
          ushort4 pk;
          pk.x = f2bf(acc[mi][ni][0] + bv[ni]);
          pk.y = f2bf(acc[mi][ni][1] + bv[ni]);
          pk.z = f2bf(acc[mi][ni][2] + bv[ni]);
          pk.w = f2bf(acc[mi][ni][3] + bv[ni]);
          size_t idx = (size_t)(B_ * H_ * L_ * D_) +
                       (((size_t)(bb * H_ + hh) * D_ + dd) * L_ + lq0);
          *(ushort4*)(ob + idx) = pk;
        } else {
#pragma unroll
          for (int r = 0; r < 4; r++) {
            size_t idx = (((size_t)(bb * H_ + hh) * L_ + lq0 + r) * D_) + dd;
            ob[idx] = f2bf((acc[mi][ni][r] + bv[ni]) * QS);
          }
        }
      }
  }
}

// fused Q + KV projection: 1536 UNIFORM 64x128 jobs, 3 blocks/CU resident.
__global__ __launch_bounds__(256, 3) void qkv_k(
    const u16* __restrict__ xb, const u16* __restrict__ yb,
    const u16* __restrict__ Wqt, const u16* __restrict__ Wkvt,
    const float* __restrict__ Wq_b, const float* __restrict__ Wkv_b,
    u16* __restrict__ Qout, u16* __restrict__ KVout)
{
  __shared__ char sA[2 * 8192];
  __shared__ char sB[2 * 16384];
  int bx = blockIdx.x, bm = blockIdx.y * 64;
  if (bx < 16)
    gemm64_body(sA, sB, yb, Wkvt, Wkv_b, (void*)KVout, 2048, 1, bm, bx * 128);
  else
    gemm64_body(sA, sB, xb, Wqt, Wq_b, (void*)Qout, 1024, 0, bm, (bx - 16) * 128);
}

// proj GEMM (epi2, f32 out): grid (8,64) = 512 uniform jobs.
__global__ __launch_bounds__(256, 3) void proj_k(
    const u16* __restrict__ A, const u16* __restrict__ Bt,
    const float* __restrict__ bias, float* __restrict__ fo)
{
  __shared__ char sA[2 * 8192];
  __shared__ char sB[2 * 16384];
  gemm64_body(sA, sB, A, Bt, bias, (void*)fo, 1024, 2,
              blockIdx.y * 64, blockIdx.x * 128);
}

// ---------------- flash attention v20: fused-phase uniform 17-tile blocks ----------
// R18 structure, but role-A's two phases run in ONE continuous k-loop (17 iters):
// tile j -> light chunk (kt=j, qbL) for j<nL, heavy suffix (kt=17+j-nL, qbH) for
// j>=nL. Buffer rotation + single-barrier invariant continue across the boundary
// (WAR proof is buffer-index-only). At block-uniform j==nL: light epilogue + state
// reset + Q reload (wave-local, no barrier; loads/stores precede next STAGE in the
// vmcnt queue so vmcnt(2) accounting is unchanged). Role B identical to R18.
__global__ __launch_bounds__(512, 2) void attn_k(
    const u16* __restrict__ Qb, const u16* __restrict__ Kb, const u16* __restrict__ Vt,
    const unsigned char* __restrict__ pad, u16* __restrict__ Ob,
    u16* __restrict__ Opart, float* __restrict__ mlbuf)
{
  __shared__ char sK[3][8192];   // [buf][key 0..63][128B row], slot s at phys s^(key&7)
  __shared__ char sV[3][8192];   // [buf][d 0..63][128B row = 64 keys], slot s^(d&7)
  __shared__ char sP[8][2048];   // per-wave P^T: [q15][128B = 64 keys], slot s^(q15&7)
  int t = threadIdx.x, lane = t & 63, w = t >> 6, g = lane >> 4, l15 = lane & 15;
  int x = blockIdx.x, h = blockIdx.y, b = blockIdx.z, bh = b * H_ + h;
  int role = x >> 3, xp = x & 7;
  int qbH = 15 - xp, qbL = xp;
  const int SPLIT = 17;
  int nL = 2 * qbL + 2;            // role A: light-chunk tile count (2..16)
  int boundary = role ? 99 : nL;   // j at which role A switches chunks

  const u16* Kbh = Kb + (size_t)bh * L_ * D_;
  const u16* Vbh = Vt + (size_t)bh * D_ * L_;
  const unsigned char* pdb = pad + b * L_;
  int psw = l15 & 7;

  // per-block pad scan (wave-uniform anyp; pad row = 2048B = 128 x 16B)
  const uint4* pp = (const uint4*)pdb;
  uint4 pv0 = pp[lane];
  uint4 pv1 = pp[64 + lane];
  uint32_t nzp = pv0.x | pv0.y | pv0.z | pv0.w | pv1.x | pv1.y | pv1.z | pv1.w;
  bool anyp = __ballot(nzp != 0) != 0;

  int srr = t >> 3, ssp = t & 7;
  int sso = (ssp ^ (srr & 7)) << 4;
#define STAGE(bufi, kt0s) do {                                                        \
    gload16((const char*)(Kbh + (size_t)((kt0s) + srr) * D_) + sso, sK[bufi] + t * 16); \
    gload16((const char*)(Vbh + (size_t)srr * L_ + (kt0s)) + sso, sV[bufi] + t * 16);   \
  } while (0)
  // key-tile base for logical tile index jj (block-uniform)
#define KT0_OF(jj) ((role ? (jj) : ((jj) < nL ? (jj) : SPLIT + (jj) - nL)) << 6)

  // initial descriptor: role B -> heavy prefix; role A -> light chunk
  int qb_cur = role ? qbH : qbL;
  int qw0 = qb_cur * 128 + w * 16;
  int bound = qw0 + 15;

  const u16* qp = Qb + ((size_t)bh * L_ + qw0 + l15) * D_ + g * 8;
  bf16x8 qf0 = *(const bf16x8*)qp;
  bf16x8 qf1 = *(const bf16x8*)(qp + 32);

  f32x4 zero = {0.f, 0.f, 0.f, 0.f};
  f32x4 oacc[4];
#pragma unroll
  for (int db = 0; db < 4; db++) oacc[db] = zero;
  float mrun = -1e30f, lrun = 0.f;

  STAGE(0, 0);
  int cb = 0, nb = 1;              // compute buf / next (stage) buf, rotate mod 3

#pragma unroll 1
  for (int j = 0; j < 17; j++) {
    __builtin_amdgcn_sched_barrier(0);
    if (j + 1 < 17) {
      STAGE(nb, KT0_OF(j + 1));                      // next tile's loads in flight
      asm volatile("s_waitcnt vmcnt(2)" ::: "memory");  // own tile-j batch landed
    } else {
      asm volatile("s_waitcnt vmcnt(0)" ::: "memory");  // last tile: full drain
    }
    __builtin_amdgcn_s_barrier();                    // all waves' tile-j loads landed
    __builtin_amdgcn_sched_barrier(0);

    if (j == boundary) {           // role A only; block-uniform scalar branch
      // ---- light-chunk epilogue (direct Ob write) ----
      float rl0 = (lrun != 0.f) ? 1.0f / lrun : 0.f;
      int q0 = qw0 + l15;
      u16* op0 = Ob + ((size_t)b * L_ + q0) * HD_ + h * D_ + g * 4;
#pragma unroll
      for (int db = 0; db < 4; db++) {
        ushort4 pk;
        pk.x = f2bf(oacc[db][0] * rl0);
        pk.y = f2bf(oacc[db][1] * rl0);
        pk.z = f2bf(oacc[db][2] * rl0);
        pk.w = f2bf(oacc[db][3] * rl0);
        *(ushort4*)(op0 + db * 16) = pk;
      }
      // ---- switch to heavy-suffix descriptor ----
      qb_cur = qbH;
      qw0 = qb_cur * 128 + w * 16;
      bound = qw0 + 15;
      const u16* qp2 = Qb + ((size_t)bh * L_ + qw0 + l15) * D_ + g * 8;
      qf0 = *(const bf16x8*)qp2;
      qf1 = *(const bf16x8*)(qp2 + 32);
#pragma unroll
      for (int db = 0; db < 4; db++) oacc[db] = zero;
      mrun = -1e30f; lrun = 0.f;
    }

    int kt0 = KT0_OF(j);
    if (kt0 <= bound) {
      // ---- S^T = mfma(K, Q): lane (g,l15) gets keys kb+4g+r at q-col l15 ----
      float sc[4][4];
#pragma unroll
      for (int s = 0; s < 4; s++) {
        int kb = kt0 + s * 16;
        bool live = (kb <= bound);
        f32x4 st = zero;
        uint32_t pb = 0;
        if (live) {
          int R = s * 16 + l15, sw = l15 & 7;
          bf16x8 kf0 = *(const bf16x8*)(sK[cb] + R * 128 + ((g ^ sw) << 4));
          bf16x8 kf1 = *(const bf16x8*)(sK[cb] + R * 128 + (((4 + g) ^ sw) << 4));
          st = MFMA16(kf0, qf0, st);
          st = MFMA16(kf1, qf1, st);
          if (anyp) pb = *(const uint32_t*)(pdb + kb + 4 * g);
        }
        // wave-uniform fast path: sub-tile fully below diagonal and no padding
        bool needm = !live || (kb + 15 > qw0) || anyp;
        if (needm) {
#pragma unroll
          for (int r = 0; r < 4; r++) {
            int key = kb + 4 * g + r;
            bool pm = (pb >> (8 * r)) & 0xffu;
            bool msk = !live || pm || (key > qw0 + l15);
            sc[s][r] = msk ? -1e30f : st[r];
          }
        } else {
#pragma unroll
          for (int r = 0; r < 4; r++) sc[s][r] = st[r];
        }
      }

      // ---- online softmax (T13 defer-rescale, THR=8) + P write ----
      float m0 = fmaxf(fmaxf(sc[0][0], sc[0][1]), fmaxf(sc[0][2], sc[0][3]));
      float m1 = fmaxf(fmaxf(sc[1][0], sc[1][1]), fmaxf(sc[1][2], sc[1][3]));
      float m2 = fmaxf(fmaxf(sc[2][0], sc[2][1]), fmaxf(sc[2][2], sc[2][3]));
      float m3 = fmaxf(fmaxf(sc[3][0], sc[3][1]), fmaxf(sc[3][2], sc[3][3]));
      float mt = fmaxf(fmaxf(m0, m1), fmaxf(m2, m3));
      mt = fmaxf(mt, __shfl_xor(mt, 16));
      mt = fmaxf(mt, __shfl_xor(mt, 32));
      if (!__all(mt <= mrun + 8.0f)) {   // wave-uniform; skip keeps P <= 2^8
        float mnew = fmaxf(mrun, mt);
        float al = __builtin_amdgcn_exp2f(mrun - mnew);
        mrun = mnew;
        lrun *= al;
#pragma unroll
        for (int db = 0; db < 4; db++)
#pragma unroll
          for (int r = 0; r < 4; r++) oacc[db][r] *= al;
      }
      float rs = 0.f;
      char* pwb = sP[w] + l15 * 128 + (g & 1) * 8;
#pragma unroll
      for (int s = 0; s < 4; s++) {
        float p0 = __builtin_amdgcn_exp2f(sc[s][0] - mrun);
        float p1 = __builtin_amdgcn_exp2f(sc[s][1] - mrun);
        float p2 = __builtin_amdgcn_exp2f(sc[s][2] - mrun);
        float p3 = __builtin_amdgcn_exp2f(sc[s][3] - mrun);
        rs += (p0 + p1) + (p2 + p3);
        uint32_t w0 = cvt_pk_bf16(p0, p1), w1 = cvt_pk_bf16(p2, p3);
        char* dst = pwb + (((2 * s + (g >> 1)) ^ psw) << 4);
        *(uint32_t*)dst = w0;
        *(uint32_t*)(dst + 4) = w1;
      }
      rs += __shfl_xor(rs, 16);
      rs += __shfl_xor(rs, 32);
      lrun += rs;

      // ---- PV: O^T += V^T . P^T ----
#pragma unroll
      for (int kc = 0; kc < 2; kc++) {
        if (kt0 + 32 * kc <= bound) {
          bf16x8 pf = *(const bf16x8*)(sP[w] + l15 * 128 + (((4 * kc + g) ^ psw) << 4));
#pragma unroll
          for (int db = 0; db < 4; db++) {
            int dR = db * 16 + l15;
            bf16x8 vf = *(const bf16x8*)(sV[cb] + dR * 128 +
                                         (((4 * kc + g) ^ (dR & 7)) << 4));
            oacc[db] = MFMA16(vf, pf, oacc[db]);
          }
        }
      }
    }
    cb = (cb == 2) ? 0 : cb + 1;
    nb = (nb == 2) ? 0 : nb + 1;
  }

  // final epilogue: heavy partial (role B -> part0; role A suffix -> part1)
  float rl = (lrun != 0.f) ? 1.0f / lrun : 0.f;   // suffix waves may have no tiles
  int q = qw0 + l15;
  int part = role ? 0 : 1;
  size_t prow = (size_t)part * 32768 + (size_t)bh * 1024 + (q - 1024);
  u16* op = Opart + prow * 64 + g * 4;
#pragma unroll
  for (int db = 0; db < 4; db++) {
    ushort4 pk;
    pk.x = f2bf(oacc[db][0] * rl);
    pk.y = f2bf(oacc[db][1] * rl);
    pk.z = f2bf(oacc[db][2] * rl);
    pk.w = f2bf(oacc[db][3] * rl);
    *(ushort4*)(op + db * 16) = pk;
  }
  if (g == 0) {
    mlbuf[prow * 2]     = mrun;   // log2-domain running max
    mlbuf[prow * 2 + 1] = lrun;
  }
#undef STAGE
#undef KT0_OF
}

// ---------------- merge of split-KV partials (rows 1024..2047 of each b) --------
__global__ __launch_bounds__(256) void merge_k(
    const u16* __restrict__ Op, const float* __restrict__ ml, u16* __restrict__ Ob)
{
  int tid = blockIdx.x * 256 + threadIdx.x;   // 262144 total
  int d0 = (tid & 7) * 8;
  int row = tid >> 3;                          // bh*1024 + qrel  (32768 rows)
  int qrel = row & 1023, bh = row >> 10;
  int b = bh >> 4, h = bh & 15;
  float m0 = ml[(size_t)row * 2],            l0 = ml[(size_t)row * 2 + 1];
  float m1 = ml[((size_t)32768 + row) * 2],  l1 = ml[((size_t)32768 + row) * 2 + 1];
  float M = fmaxf(m0, m1);
  float w0 = l0 * __builtin_amdgcn_exp2f(m0 - M);
  float w1 = l1 * __builtin_amdgcn_exp2f(m1 - M);
  float rw = 1.0f / (w0 + w1);
  w0 *= rw; w1 *= rw;
  bf16x8 a = *(const bf16x8*)(Op + (size_t)row * 64 + d0);
  bf16x8 c = *(const bf16x8*)(Op + ((size_t)32768 + row) * 64 + d0);
  bf16x8 o;
#pragma unroll
  for (int j = 0; j < 8; j++)
    o[j] = (short)f2bf(w0 * bf2f((u16)a[j]) + w1 * bf2f((u16)c[j]));
  *(bf16x8*)(Ob + ((size_t)b * L_ + 1024 + qrel) * HD_ + h * D_ + d0) = o;
}

extern "C" void kernel_launch(void* const* d_in, const int* in_sizes, int n_in,
                              void* d_out, int out_size, void* d_ws, size_t ws_size,
                              hipStream_t stream) {
  const float* x      = (const float*)d_in[0];
  const float* y      = (const float*)d_in[1];
  const unsigned char* mask = (const unsigned char*)d_in[2];
  const float* Wq_w   = (const float*)d_in[3];
  const float* Wq_b   = (const float*)d_in[4];
  const float* Wkv_w  = (const float*)d_in[5];
  const float* Wkv_b  = (const float*)d_in[6];
  const float* proj_w = (const float*)d_in[7];
  const float* proj_b = (const float*)d_in[8];

  char* ws = (char*)d_ws;
  u16* xb   = (u16*)(ws);                        // 8 MB  (reused as Ob after qkv)
  u16* yb   = (u16*)(ws + (size_t)(8  << 20));   // 8 MB  (reused as Opart after qkv)
  u16* Wqt  = (u16*)(ws + (size_t)(16 << 20));   // 2 MB  (reused as mlbuf after qkv)
  u16* Wkvt = (u16*)(ws + (size_t)(18 << 20));   // 4 MB
  u16* Wpt  = (u16*)(ws + (size_t)(22 << 20));   // 2 MB  (live until proj!)
  u16* Qb   = (u16*)(ws + (size_t)(24 << 20));   // 8 MB
  u16* Kb   = (u16*)(ws + (size_t)(32 << 20));   // 8 MB (V^T follows contiguously)
  u16* Vtb  = (u16*)(ws + (size_t)(40 << 20));   // 8 MB, layout [b,h,d,l]
  u16* Ob   = xb;
  u16* Opart  = yb;                              // dead after qkv; 8 MB exact
  float* mlbuf = (float*)Wqt;                    // dead after qkv; 512 KB of 2 MB

  hipLaunchKernelGGL(prologue_k, dim3(5120), dim3(256), 0, stream,
                     x, y, xb, yb, Wq_w, Wkv_w, proj_w, Wqt, Wkvt, Wpt);
  // fused: Q = (xb@Wq+b)*SCL -> [b,h,l,d]; KV = yb@Wkv+b -> K [b,h,l,d], V^T [b,h,d,l]
  hipLaunchKernelGGL(qkv_k, dim3(24, 64), dim3(256), 0, stream,
                     xb, yb, Wqt, Wkvt, Wq_b, Wkv_b, Qb, Kb);
  hipLaunchKernelGGL(attn_k, dim3(16, H_, B_), dim3(512), 0, stream,
                     Qb, Kb, Vtb, mask, Ob, Opart, mlbuf);
  hipLaunchKernelGGL(merge_k, dim3(1024), dim3(256), 0, stream, Opart, mlbuf, Ob);
  // out = Ob @ proj + b -> f32
  hipLaunchKernelGGL(proj_k, dim3(8, 64), dim3(256), 0, stream, Ob, Wpt, proj_b, (float*)d_out);
}

// Round 22
// 114.729 us; speedup vs baseline: 1.0144x; 1.0144x over previous
//
#include <hip/hip_runtime.h>
#include <stdint.h>

#define B_  2
#define L_  2048
#define HD_ 1024
#define H_  16
#define D_  64

typedef unsigned short u16;
typedef __attribute__((ext_vector_type(8))) short bf16x8;
typedef __attribute__((ext_vector_type(4))) float f32x4;

#define MFMA16(a, b, c) __builtin_amdgcn_mfma_f32_16x16x32_bf16((a), (b), (c), 0, 0, 0)

__device__ __forceinline__ void gload16(const void* g, void* l) {
  __builtin_amdgcn_global_load_lds((const __attribute__((address_space(1))) void*)g,
                                   (__attribute__((address_space(3))) void*)l, 16, 0, 0);
}

__device__ __forceinline__ u16 f2bf(float f) {
  union { float f; uint32_t u; } c; c.f = f;
  uint32_t u = c.u + 0x7FFFu + ((c.u >> 16) & 1u);
  return (u16)(u >> 16);
}

__device__ __forceinline__ float bf2f(u16 v) {
  union { uint32_t u; float f; } c; c.u = (uint32_t)v << 16;
  return c.f;
}

__device__ __forceinline__ uint32_t cvt_pk_bf16(float lo, float hi) {
  uint32_t r;
  asm("v_cvt_pk_bf16_f32 %0, %1, %2" : "=v"(r) : "v"(lo), "v"(hi));
  return r;
}

// ---------------- fused prologue (R20 vectorized version — passed) ----------------
// blocks 0..4095: cast. blocks 4096..5119: 64x64 transpose tiles, float4 reads +
// ushort4 writes: Wq 256 tiles, Wkv 512, Wp 256.
__global__ void prologue_k(const float* __restrict__ x, const float* __restrict__ y,
                           u16* __restrict__ xb, u16* __restrict__ yb,
                           const float* __restrict__ Wq, const float* __restrict__ Wkv,
                           const float* __restrict__ Wp,
                           u16* __restrict__ Wqt, u16* __restrict__ Wkvt,
                           u16* __restrict__ Wpt) {
  int bid = blockIdx.x;
  int t = threadIdx.x;
  if (bid < 4096) {
    const float* in = bid < 2048 ? x : y;
    u16* out = bid < 2048 ? xb : yb;
    int i = ((bid & 2047) * 256 + t) * 8;   // 2048*256*8 == 4M exact
    float4 a = *(const float4*)(in + i);
    float4 b = *(const float4*)(in + i + 4);
    bf16x8 r;
    r[0] = (short)f2bf(a.x); r[1] = (short)f2bf(a.y); r[2] = (short)f2bf(a.z); r[3] = (short)f2bf(a.w);
    r[4] = (short)f2bf(b.x); r[5] = (short)f2bf(b.y); r[6] = (short)f2bf(b.z); r[7] = (short)f2bf(b.w);
    *(bf16x8*)(out + i) = r;
    return;                                 // block-uniform, before any barrier
  }
  int f = bid - 4096;
  const float* src; u16* dst; int Nfull, bx, by;
  if (f < 256)      { src = Wq;  dst = Wqt;  Nfull = 1024; bx = f & 15;  by = f >> 4; }
  else if (f < 768) { int g2 = f - 256; src = Wkv; dst = Wkvt; Nfull = 2048; bx = g2 & 31; by = g2 >> 5; }
  else              { int g2 = f - 768; src = Wp;  dst = Wpt;  Nfull = 1024; bx = g2 & 15; by = g2 >> 4; }
  __shared__ float tile[64][65];
  int c = t & 15, r = t >> 4;               // c: 16 float4 cols, r: 16 rows/pass
  int nb = bx * 64, kb = by * 64;
#pragma unroll
  for (int i = 0; i < 4; i++) {
    float4 v = *(const float4*)(src + (size_t)(kb + r + i * 16) * Nfull + nb + c * 4);
    tile[r + i * 16][c * 4 + 0] = v.x;
    tile[r + i * 16][c * 4 + 1] = v.y;
    tile[r + i * 16][c * 4 + 2] = v.z;
    tile[r + i * 16][c * 4 + 3] = v.w;
  }
  __syncthreads();
#pragma unroll
  for (int i = 0; i < 4; i++) {
    int nl = r + i * 16;                    // dst row = n index within tile
    ushort4 o;
    o.x = f2bf(tile[c * 4 + 0][nl]);
    o.y = f2bf(tile[c * 4 + 1][nl]);
    o.z = f2bf(tile[c * 4 + 2][nl]);
    o.w = f2bf(tile[c * 4 + 3][nl]);
    *(ushort4*)(dst + (size_t)(nb + nl) * 1024 + kb + c * 4) = o;
  }
}

// ---------------- 64-row GEMM body (proven R19) --------------
__device__ __forceinline__ void gemm64_body(
    char* sA, char* sB,                 // sA 2*8192, sB 2*16384
    const u16* __restrict__ A, const u16* __restrict__ Bt,
    const float* __restrict__ bias, void* __restrict__ outp,
    int N, int epi, int bm, int bn)
{
  int t = threadIdx.x;
  int lane = t & 63, w = t >> 6;
  int g = lane >> 4, l15 = lane & 15;
  int wr = w >> 1, wc = w & 1;

  f32x4 zero = {0.f, 0.f, 0.f, 0.f};
  f32x4 acc[2][4];
#pragma unroll
  for (int mi = 0; mi < 2; mi++)
#pragma unroll
    for (int ni = 0; ni < 4; ni++) acc[mi][ni] = zero;

#define GSTAGE64(bufi, k0s) do {                                                        \
    _Pragma("unroll")                                                                   \
    for (int it = 0; it < 2; it++) {      /* A: 512 chunks (64 rows x 8 slots) */       \
      int c = it * 256 + t;                                                             \
      int r = c >> 3, sp = c & 7;                                                       \
      int off = (sp ^ (r & 7)) << 4;                                                    \
      gload16((const char*)(A + (size_t)(bm + r) * 1024 + (k0s)) + off,                 \
              sA + (bufi) * 8192 + c * 16);                                             \
    }                                                                                   \
    _Pragma("unroll")                                                                   \
    for (int it = 0; it < 4; it++) {      /* B: 1024 chunks (128 rows x 8 slots) */     \
      int c = it * 256 + t;                                                             \
      int r = c >> 3, sp = c & 7;                                                       \
      int off = (sp ^ (r & 7)) << 4;                                                    \
      gload16((const char*)(Bt + (size_t)(bn + r) * 1024 + (k0s)) + off,                \
              sB + (bufi) * 16384 + c * 16);                                            \
    } } while (0)

  GSTAGE64(0, 0);
  int buf = 0;
#pragma unroll 1
  for (int kt = 0; kt < 16; kt++) {
    __builtin_amdgcn_sched_barrier(0);
    __builtin_amdgcn_s_barrier();                      // B1: buf^1 free to overwrite
    if (kt < 15) {
      GSTAGE64(buf ^ 1, (kt + 1) << 6);                // next tile's 6 loads in flight
      asm volatile("s_waitcnt vmcnt(6)" ::: "memory"); // own tile's batch landed
    } else {
      asm volatile("s_waitcnt vmcnt(0)" ::: "memory"); // last tile: full drain
    }
    __builtin_amdgcn_s_barrier();                      // B2: tile kt resident block-wide
    __builtin_amdgcn_sched_barrier(0);

    const char* cA = sA + buf * 8192;
    const char* cB = sB + buf * 16384;
#pragma unroll
    for (int kc = 0; kc < 2; kc++) {
      bf16x8 af[2], bfr[4];
#pragma unroll
      for (int mi = 0; mi < 2; mi++) {
        int r = wr * 32 + mi * 16 + l15;
        af[mi] = *(const bf16x8*)(cA + r * 128 + (((kc * 4 + g) ^ (r & 7)) << 4));
      }
#pragma unroll
      for (int ni = 0; ni < 4; ni++) {
        int r = wc * 64 + ni * 16 + l15;
        bfr[ni] = *(const bf16x8*)(cB + r * 128 + (((kc * 4 + g) ^ (r & 7)) << 4));
      }
#pragma unroll
      for (int mi = 0; mi < 2; mi++)
#pragma unroll
        for (int ni = 0; ni < 4; ni++)
          acc[mi][ni] = MFMA16(af[mi], bfr[ni], acc[mi][ni]);
    }
    buf ^= 1;
  }
#undef GSTAGE64

  float bv[4];
#pragma unroll
  for (int ni = 0; ni < 4; ni++) bv[ni] = bias[bn + wc * 64 + ni * 16 + l15];

  if (epi == 2) {
    float* fo = (float*)outp;
#pragma unroll
    for (int mi = 0; mi < 2; mi++)
#pragma unroll
      for (int ni = 0; ni < 4; ni++) {
        int n = bn + wc * 64 + ni * 16 + l15;
#pragma unroll
        for (int r = 0; r < 4; r++) {
          int m = bm + wr * 32 + mi * 16 + g * 4 + r;
          fo[(size_t)m * N + n] = acc[mi][ni][r] + bv[ni];
        }
      }
  } else {
    const float QS = (epi == 0) ? 0.125f * 1.44269504089f : 1.0f;  // fold attn scale into Q
    u16* ob = (u16*)outp;
#pragma unroll
    for (int mi = 0; mi < 2; mi++)
#pragma unroll
      for (int ni = 0; ni < 4; ni++) {
        int n = bn + wc * 64 + ni * 16 + l15;
        int kv = n >> 10;          // 0 for epi0 (N=1024)
        int hh = (n >> 6) & 15;
        int dd = n & 63;
        int m0 = bm + wr * 32 + mi * 16 + g * 4;
        int bb = m0 >> 11, lq0 = m0 & 2047;
        if (epi == 1 && kv == 1) {
          // V stored TRANSPOSED: [b,h,d,l]; r -> lq consecutive -> one 8B store
          ushort4 pk;
          pk.x = f2bf(acc[mi][ni][0] + bv[ni]);
          pk.y = f2bf(acc[mi][ni][1] + bv[ni]);
          pk.z = f2bf(acc[mi][ni][2] + bv[ni]);
          pk.w = f2bf(acc[mi][ni][3] + bv[ni]);
          size_t idx = (size_t)(B_ * H_ * L_ * D_) +
                       (((size_t)(bb * H_ + hh) * D_ + dd) * L_ + lq0);
          *(ushort4*)(ob + idx) = pk;
        } else {
#pragma unroll
          for (int r = 0; r < 4; r++) {
            size_t idx = (((size_t)(bb * H_ + hh) * L_ + lq0 + r) * D_) + dd;
            ob[idx] = f2bf((acc[mi][ni][r] + bv[ni]) * QS);
          }
        }
      }
  }
}

// fused Q + KV projection: 1536 UNIFORM 64x128 jobs, 3 blocks/CU resident.
__global__ __launch_bounds__(256, 3) void qkv_k(
    const u16* __restrict__ xb, const u16* __restrict__ yb,
    const u16* __restrict__ Wqt, const u16* __restrict__ Wkvt,
    const float* __restrict__ Wq_b, const float* __restrict__ Wkv_b,
    u16* __restrict__ Qout, u16* __restrict__ KVout)
{
  __shared__ char sA[2 * 8192];
  __shared__ char sB[2 * 16384];
  int bx = blockIdx.x, bm = blockIdx.y * 64;
  if (bx < 16)
    gemm64_body(sA, sB, yb, Wkvt, Wkv_b, (void*)KVout, 2048, 1, bm, bx * 128);
  else
    gemm64_body(sA, sB, xb, Wqt, Wq_b, (void*)Qout, 1024, 0, bm, (bx - 16) * 128);
}

// proj GEMM (epi2, f32 out): grid (8,64) = 512 uniform jobs.
__global__ __launch_bounds__(256, 3) void proj_k(
    const u16* __restrict__ A, const u16* __restrict__ Bt,
    const float* __restrict__ bias, float* __restrict__ fo)
{
  __shared__ char sA[2 * 8192];
  __shared__ char sB[2 * 16384];
  gemm64_body(sA, sB, A, Bt, bias, (void*)fo, 1024, 2,
              blockIdx.y * 64, blockIdx.x * 128);
}

// ---------------- flash attention (verbatim R18/R19 version — passed @42.0us) ------
// Uniform 17-tile blocks: role B = heavy prefix [0,17) -> partial part0;
// role A = light chunk full (-> Ob) then heavy suffix [17,nktH) -> partial part1.
// Triple-buffer single-barrier k-loop, counted vmcnt(2), T13 THR=8, pad hoist,
// prescaled Q.
__global__ __launch_bounds__(512, 2) void attn_k(
    const u16* __restrict__ Qb, const u16* __restrict__ Kb, const u16* __restrict__ Vt,
    const unsigned char* __restrict__ pad, u16* __restrict__ Ob,
    u16* __restrict__ Opart, float* __restrict__ mlbuf)
{
  __shared__ char sK[3][8192];   // [buf][key 0..63][128B row], slot s at phys s^(key&7)
  __shared__ char sV[3][8192];   // [buf][d 0..63][128B row = 64 keys], slot s^(d&7)
  __shared__ char sP[8][2048];   // per-wave P^T: [q15][128B = 64 keys], slot s^(q15&7)
  int t = threadIdx.x, lane = t & 63, w = t >> 6, g = lane >> 4, l15 = lane & 15;
  int x = blockIdx.x, h = blockIdx.y, b = blockIdx.z, bh = b * H_ + h;
  int role = x >> 3, xp = x & 7;
  int qbH = 15 - xp, qbL = xp;
  int nktH = 2 * qbH + 2;        // 18..32
  const int SPLIT = 17;

  const u16* Kbh = Kb + (size_t)bh * L_ * D_;
  const u16* Vbh = Vt + (size_t)bh * D_ * L_;
  const unsigned char* pdb = pad + b * L_;
  int psw = l15 & 7;

  // per-block pad scan (wave-uniform anyp; pad row = 2048B = 128 x 16B)
  const uint4* pp = (const uint4*)pdb;
  uint4 pv0 = pp[lane];
  uint4 pv1 = pp[64 + lane];
  uint32_t nzp = pv0.x | pv0.y | pv0.z | pv0.w | pv1.x | pv1.y | pv1.z | pv1.w;
  bool anyp = __ballot(nzp != 0) != 0;

  // staging (512 threads): 1 K-chunk + 1 V-chunk per thread; chunk t -> row t>>3,
  // 16B slot t&7 (source pre-swizzled, LDS dest linear — T2 both-sides rule)
  int srr = t >> 3, ssp = t & 7;
  int sso = (ssp ^ (srr & 7)) << 4;
#define STAGE(bufi, kt0s) do {                                                        \
    gload16((const char*)(Kbh + (size_t)((kt0s) + srr) * D_) + sso, sK[bufi] + t * 16); \
    gload16((const char*)(Vbh + (size_t)srr * L_ + (kt0s)) + sso, sV[bufi] + t * 16);   \
  } while (0)

  int nphase = role ? 1 : 2;
#pragma unroll 1
  for (int ph = 0; ph < nphase; ph++) {
    int qb, lo, hi, mode;
    if (role) { qb = qbH; lo = 0;     hi = SPLIT;     mode = 1; }  // heavy prefix
    else if (ph == 0) { qb = qbL; lo = 0; hi = 2 * qbL + 2; mode = 0; }  // light full
    else { qb = qbH; lo = SPLIT; hi = nktH; mode = 2; }            // heavy suffix

    int qw0 = qb * 128 + w * 16;
    int bound = qw0 + 15;         // last q-row this wave owns

    // Q fragments: qf[dc] covers d = dc*32 + g*8 .. +7 at q-row qw0 + l15
    const u16* qp = Qb + ((size_t)bh * L_ + qw0 + l15) * D_ + g * 8;
    bf16x8 qf0 = *(const bf16x8*)qp;
    bf16x8 qf1 = *(const bf16x8*)(qp + 32);

    f32x4 zero = {0.f, 0.f, 0.f, 0.f};
    f32x4 oacc[4];
#pragma unroll
    for (int db = 0; db < 4; db++) oacc[db] = zero;
    float mrun = -1e30f, lrun = 0.f;

    if (ph) __syncthreads();      // phase boundary: all waves done with buffers
    STAGE(0, lo << 6);
    int cb = 0, nb = 1;           // compute buf / next (stage) buf, rotate mod 3

#pragma unroll 1
    for (int kt = lo; kt < hi; kt++) {
      int kt0 = kt << 6;
      __builtin_amdgcn_sched_barrier(0);
      if (kt + 1 < hi) {
        STAGE(nb, (kt + 1) << 6);                      // next tile's loads in flight
        asm volatile("s_waitcnt vmcnt(2)" ::: "memory");  // own tile-kt batch landed
      } else {
        asm volatile("s_waitcnt vmcnt(0)" ::: "memory");  // last tile: full drain
      }
      __builtin_amdgcn_s_barrier();                    // all waves' tile-kt loads landed
      __builtin_amdgcn_sched_barrier(0);

      if (kt0 <= bound) {
        // ---- S^T = mfma(K, Q): lane (g,l15) gets keys kb+4g+r at q-col l15 ----
        float sc[4][4];
#pragma unroll
        for (int s = 0; s < 4; s++) {
          int kb = kt0 + s * 16;
          bool live = (kb <= bound);
          f32x4 st = zero;
          uint32_t pb = 0;
          if (live) {
            int R = s * 16 + l15, sw = l15 & 7;
            bf16x8 kf0 = *(const bf16x8*)(sK[cb] + R * 128 + ((g ^ sw) << 4));
            bf16x8 kf1 = *(const bf16x8*)(sK[cb] + R * 128 + (((4 + g) ^ sw) << 4));
            st = MFMA16(kf0, qf0, st);
            st = MFMA16(kf1, qf1, st);
            if (anyp) pb = *(const uint32_t*)(pdb + kb + 4 * g);
          }
          // wave-uniform fast path: sub-tile fully below diagonal and no padding
          bool needm = !live || (kb + 15 > qw0) || anyp;
          if (needm) {
#pragma unroll
            for (int r = 0; r < 4; r++) {
              int key = kb + 4 * g + r;
              bool pm = (pb >> (8 * r)) & 0xffu;
              bool msk = !live || pm || (key > qw0 + l15);
              sc[s][r] = msk ? -1e30f : st[r];
            }
          } else {
#pragma unroll
            for (int r = 0; r < 4; r++) sc[s][r] = st[r];
          }
        }

        // ---- online softmax (T13 defer-rescale, THR=8) + P write ----
        float m0 = fmaxf(fmaxf(sc[0][0], sc[0][1]), fmaxf(sc[0][2], sc[0][3]));
        float m1 = fmaxf(fmaxf(sc[1][0], sc[1][1]), fmaxf(sc[1][2], sc[1][3]));
        float m2 = fmaxf(fmaxf(sc[2][0], sc[2][1]), fmaxf(sc[2][2], sc[2][3]));
        float m3 = fmaxf(fmaxf(sc[3][0], sc[3][1]), fmaxf(sc[3][2], sc[3][3]));
        float mt = fmaxf(fmaxf(m0, m1), fmaxf(m2, m3));
        mt = fmaxf(mt, __shfl_xor(mt, 16));
        mt = fmaxf(mt, __shfl_xor(mt, 32));
        if (!__all(mt <= mrun + 8.0f)) {   // wave-uniform; skip keeps P <= 2^8
          float mnew = fmaxf(mrun, mt);
          float al = __builtin_amdgcn_exp2f(mrun - mnew);
          mrun = mnew;
          lrun *= al;
#pragma unroll
          for (int db = 0; db < 4; db++)
#pragma unroll
            for (int r = 0; r < 4; r++) oacc[db][r] *= al;
        }
        float rs = 0.f;
        char* pwb = sP[w] + l15 * 128 + (g & 1) * 8;
#pragma unroll
        for (int s = 0; s < 4; s++) {
          float p0 = __builtin_amdgcn_exp2f(sc[s][0] - mrun);
          float p1 = __builtin_amdgcn_exp2f(sc[s][1] - mrun);
          float p2 = __builtin_amdgcn_exp2f(sc[s][2] - mrun);
          float p3 = __builtin_amdgcn_exp2f(sc[s][3] - mrun);
          rs += (p0 + p1) + (p2 + p3);
          uint32_t w0 = cvt_pk_bf16(p0, p1), w1 = cvt_pk_bf16(p2, p3);
          char* dst = pwb + (((2 * s + (g >> 1)) ^ psw) << 4);
          *(uint32_t*)dst = w0;
          *(uint32_t*)(dst + 4) = w1;
        }
        rs += __shfl_xor(rs, 16);
        rs += __shfl_xor(rs, 32);
        lrun += rs;

        // ---- PV: O^T += V^T . P^T ----
#pragma unroll
        for (int kc = 0; kc < 2; kc++) {
          if (kt0 + 32 * kc <= bound) {
            bf16x8 pf = *(const bf16x8*)(sP[w] + l15 * 128 + (((4 * kc + g) ^ psw) << 4));
#pragma unroll
            for (int db = 0; db < 4; db++) {
              int dR = db * 16 + l15;
              bf16x8 vf = *(const bf16x8*)(sV[cb] + dR * 128 +
                                           (((4 * kc + g) ^ (dR & 7)) << 4));
              oacc[db] = MFMA16(vf, pf, oacc[db]);
            }
          }
        }
      }
      cb = (cb == 2) ? 0 : cb + 1;
      nb = (nb == 2) ? 0 : nb + 1;
    }

    // epilogue: lane holds O^T[d = db*16 + g*4 + r][q = qw0 + l15]
    float rl = (lrun != 0.f) ? 1.0f / lrun : 0.f;   // suffix waves may have no tiles
    int q = qw0 + l15;
    if (mode == 0) {
      u16* op = Ob + ((size_t)b * L_ + q) * HD_ + h * D_ + g * 4;
#pragma unroll
      for (int db = 0; db < 4; db++) {
        ushort4 pk;
        pk.x = f2bf(oacc[db][0] * rl);
        pk.y = f2bf(oacc[db][1] * rl);
        pk.z = f2bf(oacc[db][2] * rl);
        pk.w = f2bf(oacc[db][3] * rl);
        *(ushort4*)(op + db * 16) = pk;
      }
    } else {
      int part = mode - 1;
      size_t prow = (size_t)part * 32768 + (size_t)bh * 1024 + (q - 1024);
      u16* op = Opart + prow * 64 + g * 4;
#pragma unroll
      for (int db = 0; db < 4; db++) {
        ushort4 pk;
        pk.x = f2bf(oacc[db][0] * rl);
        pk.y = f2bf(oacc[db][1] * rl);
        pk.z = f2bf(oacc[db][2] * rl);
        pk.w = f2bf(oacc[db][3] * rl);
        *(ushort4*)(op + db * 16) = pk;
      }
      if (g == 0) {
        mlbuf[prow * 2]     = mrun;   // log2-domain running max
        mlbuf[prow * 2 + 1] = lrun;
      }
    }
  }
#undef STAGE
}

// ---------------- merge of split-KV partials (rows 1024..2047 of each b) --------
__global__ __launch_bounds__(256) void merge_k(
    const u16* __restrict__ Op, const float* __restrict__ ml, u16* __restrict__ Ob)
{
  int tid = blockIdx.x * 256 + threadIdx.x;   // 262144 total
  int d0 = (tid & 7) * 8;
  int row = tid >> 3;                          // bh*1024 + qrel  (32768 rows)
  int qrel = row & 1023, bh = row >> 10;
  int b = bh >> 4, h = bh & 15;
  float m0 = ml[(size_t)row * 2],            l0 = ml[(size_t)row * 2 + 1];
  float m1 = ml[((size_t)32768 + row) * 2],  l1 = ml[((size_t)32768 + row) * 2 + 1];
  float M = fmaxf(m0, m1);
  float w0 = l0 * __builtin_amdgcn_exp2f(m0 - M);
  float w1 = l1 * __builtin_amdgcn_exp2f(m1 - M);
  float rw = 1.0f / (w0 + w1);
  w0 *= rw; w1 *= rw;
  bf16x8 a = *(const bf16x8*)(Op + (size_t)row * 64 + d0);
  bf16x8 c = *(const bf16x8*)(Op + ((size_t)32768 + row) * 64 + d0);
  bf16x8 o;
#pragma unroll
  for (int j = 0; j < 8; j++)
    o[j] = (short)f2bf(w0 * bf2f((u16)a[j]) + w1 * bf2f((u16)c[j]));
  *(bf16x8*)(Ob + ((size_t)b * L_ + 1024 + qrel) * HD_ + h * D_ + d0) = o;
}

extern "C" void kernel_launch(void* const* d_in, const int* in_sizes, int n_in,
                              void* d_out, int out_size, void* d_ws, size_t ws_size,
                              hipStream_t stream) {
  const float* x      = (const float*)d_in[0];
  const float* y      = (const float*)d_in[1];
  const unsigned char* mask = (const unsigned char*)d_in[2];
  const float* Wq_w   = (const float*)d_in[3];
  const float* Wq_b   = (const float*)d_in[4];
  const float* Wkv_w  = (const float*)d_in[5];
  const float* Wkv_b  = (const float*)d_in[6];
  const float* proj_w = (const float*)d_in[7];
  const float* proj_b = (const float*)d_in[8];

  char* ws = (char*)d_ws;
  u16* xb   = (u16*)(ws);                        // 8 MB  (reused as Ob after qkv)
  u16* yb   = (u16*)(ws + (size_t)(8  << 20));   // 8 MB  (reused as Opart after qkv)
  u16* Wqt  = (u16*)(ws + (size_t)(16 << 20));   // 2 MB  (reused as mlbuf after qkv)
  u16* Wkvt = (u16*)(ws + (size_t)(18 << 20));   // 4 MB
  u16* Wpt  = (u16*)(ws + (size_t)(22 << 20));   // 2 MB  (live until proj!)
  u16* Qb   = (u16*)(ws + (size_t)(24 << 20));   // 8 MB
  u16* Kb   = (u16*)(ws + (size_t)(32 << 20));   // 8 MB (V^T follows contiguously)
  u16* Vtb  = (u16*)(ws + (size_t)(40 << 20));   // 8 MB, layout [b,h,d,l]
  u16* Ob   = xb;
  u16* Opart  = yb;                              // dead after qkv; 8 MB exact
  float* mlbuf = (float*)Wqt;                    // dead after qkv; 512 KB of 2 MB

  hipLaunchKernelGGL(prologue_k, dim3(5120), dim3(256), 0, stream,
                     x, y, xb, yb, Wq_w, Wkv_w, proj_w, Wqt, Wkvt, Wpt);
  // fused: Q = (xb@Wq+b)*SCL -> [b,h,l,d]; KV = yb@Wkv+b -> K [b,h,l,d], V^T [b,h,d,l]
  hipLaunchKernelGGL(qkv_k, dim3(24, 64), dim3(256), 0, stream,
                     xb, yb, Wqt, Wkvt, Wq_b, Wkv_b, Qb, Kb);
  hipLaunchKernelGGL(attn_k, dim3(16, H_, B_), dim3(512), 0, stream,
                     Qb, Kb, Vtb, mask, Ob, Opart, mlbuf);
  hipLaunchKernelGGL(merge_k, dim3(1024), dim3(256), 0, stream, Opart, mlbuf, Ob);
  // out = Ob @ proj + b -> f32
  hipLaunchKernelGGL(proj_k, dim3(8, 64), dim3(256), 0, stream, Ob, Wpt, proj_b, (float*)d_out);
}

// Round 23
// 113.777 us; speedup vs baseline: 1.0229x; 1.0084x over previous
//
#include <hip/hip_runtime.h>
#include <stdint.h>

#define B_  2
#define L_  2048
#define HD_ 1024
#define H_  16
#define D_  64

typedef unsigned short u16;
typedef __attribute__((ext_vector_type(8))) short bf16x8;
typedef __attribute__((ext_vector_type(4))) float f32x4;

#define MFMA16(a, b, c) __builtin_amdgcn_mfma_f32_16x16x32_bf16((a), (b), (c), 0, 0, 0)

__device__ __forceinline__ void gload16(const void* g, void* l) {
  __builtin_amdgcn_global_load_lds((const __attribute__((address_space(1))) void*)g,
                                   (__attribute__((address_space(3))) void*)l, 16, 0, 0);
}

__device__ __forceinline__ u16 f2bf(float f) {
  union { float f; uint32_t u; } c; c.f = f;
  uint32_t u = c.u + 0x7FFFu + ((c.u >> 16) & 1u);
  return (u16)(u >> 16);
}

__device__ __forceinline__ float bf2f(u16 v) {
  union { uint32_t u; float f; } c; c.u = (uint32_t)v << 16;
  return c.f;
}

__device__ __forceinline__ uint32_t cvt_pk_bf16(float lo, float hi) {
  uint32_t r;
  asm("v_cvt_pk_bf16_f32 %0, %1, %2" : "=v"(r) : "v"(lo), "v"(hi));
  return r;
}

// ---------------- fused prologue (vectorized — proven R20/R21) ----------------
__global__ void prologue_k(const float* __restrict__ x, const float* __restrict__ y,
                           u16* __restrict__ xb, u16* __restrict__ yb,
                           const float* __restrict__ Wq, const float* __restrict__ Wkv,
                           const float* __restrict__ Wp,
                           u16* __restrict__ Wqt, u16* __restrict__ Wkvt,
                           u16* __restrict__ Wpt) {
  int bid = blockIdx.x;
  int t = threadIdx.x;
  if (bid < 4096) {
    const float* in = bid < 2048 ? x : y;
    u16* out = bid < 2048 ? xb : yb;
    int i = ((bid & 2047) * 256 + t) * 8;   // 2048*256*8 == 4M exact
    float4 a = *(const float4*)(in + i);
    float4 b = *(const float4*)(in + i + 4);
    bf16x8 r;
    r[0] = (short)f2bf(a.x); r[1] = (short)f2bf(a.y); r[2] = (short)f2bf(a.z); r[3] = (short)f2bf(a.w);
    r[4] = (short)f2bf(b.x); r[5] = (short)f2bf(b.y); r[6] = (short)f2bf(b.z); r[7] = (short)f2bf(b.w);
    *(bf16x8*)(out + i) = r;
    return;                                 // block-uniform, before any barrier
  }
  int f = bid - 4096;
  const float* src; u16* dst; int Nfull, bx, by;
  if (f < 256)      { src = Wq;  dst = Wqt;  Nfull = 1024; bx = f & 15;  by = f >> 4; }
  else if (f < 768) { int g2 = f - 256; src = Wkv; dst = Wkvt; Nfull = 2048; bx = g2 & 31; by = g2 >> 5; }
  else              { int g2 = f - 768; src = Wp;  dst = Wpt;  Nfull = 1024; bx = g2 & 15; by = g2 >> 4; }
  __shared__ float tile[64][65];
  int c = t & 15, r = t >> 4;               // c: 16 float4 cols, r: 16 rows/pass
  int nb = bx * 64, kb = by * 64;
#pragma unroll
  for (int i = 0; i < 4; i++) {
    float4 v = *(const float4*)(src + (size_t)(kb + r + i * 16) * Nfull + nb + c * 4);
    tile[r + i * 16][c * 4 + 0] = v.x;
    tile[r + i * 16][c * 4 + 1] = v.y;
    tile[r + i * 16][c * 4 + 2] = v.z;
    tile[r + i * 16][c * 4 + 3] = v.w;
  }
  __syncthreads();
#pragma unroll
  for (int i = 0; i < 4; i++) {
    int nl = r + i * 16;                    // dst row = n index within tile
    ushort4 o;
    o.x = f2bf(tile[c * 4 + 0][nl]);
    o.y = f2bf(tile[c * 4 + 1][nl]);
    o.z = f2bf(tile[c * 4 + 2][nl]);
    o.w = f2bf(tile[c * 4 + 3][nl]);
    *(ushort4*)(dst + (size_t)(nb + nl) * 1024 + kb + c * 4) = o;
  }
}

// ---------------- 64-row GEMM body (proven R19) --------------
__device__ __forceinline__ void gemm64_body(
    char* sA, char* sB,                 // sA 2*8192, sB 2*16384
    const u16* __restrict__ A, const u16* __restrict__ Bt,
    const float* __restrict__ bias, void* __restrict__ outp,
    int N, int epi, int bm, int bn)
{
  int t = threadIdx.x;
  int lane = t & 63, w = t >> 6;
  int g = lane >> 4, l15 = lane & 15;
  int wr = w >> 1, wc = w & 1;

  f32x4 zero = {0.f, 0.f, 0.f, 0.f};
  f32x4 acc[2][4];
#pragma unroll
  for (int mi = 0; mi < 2; mi++)
#pragma unroll
    for (int ni = 0; ni < 4; ni++) acc[mi][ni] = zero;

#define GSTAGE64(bufi, k0s) do {                                                        \
    _Pragma("unroll")                                                                   \
    for (int it = 0; it < 2; it++) {      /* A: 512 chunks (64 rows x 8 slots) */       \
      int c = it * 256 + t;                                                             \
      int r = c >> 3, sp = c & 7;                                                       \
      int off = (sp ^ (r & 7)) << 4;                                                    \
      gload16((const char*)(A + (size_t)(bm + r) * 1024 + (k0s)) + off,                 \
              sA + (bufi) * 8192 + c * 16);                                             \
    }                                                                                   \
    _Pragma("unroll")                                                                   \
    for (int it = 0; it < 4; it++) {      /* B: 1024 chunks (128 rows x 8 slots) */     \
      int c = it * 256 + t;                                                             \
      int r = c >> 3, sp = c & 7;                                                       \
      int off = (sp ^ (r & 7)) << 4;                                                    \
      gload16((const char*)(Bt + (size_t)(bn + r) * 1024 + (k0s)) + off,                \
              sB + (bufi) * 16384 + c * 16);                                            \
    } } while (0)

  GSTAGE64(0, 0);
  int buf = 0;
#pragma unroll 1
  for (int kt = 0; kt < 16; kt++) {
    __builtin_amdgcn_sched_barrier(0);
    __builtin_amdgcn_s_barrier();                      // B1: buf^1 free to overwrite
    if (kt < 15) {
      GSTAGE64(buf ^ 1, (kt + 1) << 6);                // next tile's 6 loads in flight
      asm volatile("s_waitcnt vmcnt(6)" ::: "memory"); // own tile's batch landed
    } else {
      asm volatile("s_waitcnt vmcnt(0)" ::: "memory"); // last tile: full drain
    }
    __builtin_amdgcn_s_barrier();                      // B2: tile kt resident block-wide
    __builtin_amdgcn_sched_barrier(0);

    const char* cA = sA + buf * 8192;
    const char* cB = sB + buf * 16384;
#pragma unroll
    for (int kc = 0; kc < 2; kc++) {
      bf16x8 af[2], bfr[4];
#pragma unroll
      for (int mi = 0; mi < 2; mi++) {
        int r = wr * 32 + mi * 16 + l15;
        af[mi] = *(const bf16x8*)(cA + r * 128 + (((kc * 4 + g) ^ (r & 7)) << 4));
      }
#pragma unroll
      for (int ni = 0; ni < 4; ni++) {
        int r = wc * 64 + ni * 16 + l15;
        bfr[ni] = *(const bf16x8*)(cB + r * 128 + (((kc * 4 + g) ^ (r & 7)) << 4));
      }
#pragma unroll
      for (int mi = 0; mi < 2; mi++)
#pragma unroll
        for (int ni = 0; ni < 4; ni++)
          acc[mi][ni] = MFMA16(af[mi], bfr[ni], acc[mi][ni]);
    }
    buf ^= 1;
  }
#undef GSTAGE64

  float bv[4];
#pragma unroll
  for (int ni = 0; ni < 4; ni++) bv[ni] = bias[bn + wc * 64 + ni * 16 + l15];

  if (epi == 2) {
    float* fo = (float*)outp;
#pragma unroll
    for (int mi = 0; mi < 2; mi++)
#pragma unroll
      for (int ni = 0; ni < 4; ni++) {
        int n = bn + wc * 64 + ni * 16 + l15;
#pragma unroll
        for (int r = 0; r < 4; r++) {
          int m = bm + wr * 32 + mi * 16 + g * 4 + r;
          fo[(size_t)m * N + n] = acc[mi][ni][r] + bv[ni];
        }
      }
  } else {
    const float QS = (epi == 0) ? 0.125f * 1.44269504089f : 1.0f;  // fold attn scale into Q
    u16* ob = (u16*)outp;
#pragma unroll
    for (int mi = 0; mi < 2; mi++)
#pragma unroll
      for (int ni = 0; ni < 4; ni++) {
        int n = bn + wc * 64 + ni * 16 + l15;
        int kv = n >> 10;          // 0 for epi0 (N=1024)
        int hh = (n >> 6) & 15;
        int dd = n & 63;
        int m0 = bm + wr * 32 + mi * 16 + g * 4;
        int bb = m0 >> 11, lq0 = m0 & 2047;
        if (epi == 1 && kv == 1) {
          // V stored TRANSPOSED: [b,h,d,l]; r -> lq consecutive -> one 8B store
          ushort4 pk;
          pk.x = f2bf(acc[mi][ni][0] + bv[ni]);
          pk.y = f2bf(acc[mi][ni][1] + bv[ni]);
          pk.z = f2bf(acc[mi][ni][2] + bv[ni]);
          pk.w = f2bf(acc[mi][ni][3] + bv[ni]);
          size_t idx = (size_t)(B_ * H_ * L_ * D_) +
                       (((size_t)(bb * H_ + hh) * D_ + dd) * L_ + lq0);
          *(ushort4*)(ob + idx) = pk;
        } else {
#pragma unroll
          for (int r = 0; r < 4; r++) {
            size_t idx = (((size_t)(bb * H_ + hh) * L_ + lq0 + r) * D_) + dd;
            ob[idx] = f2bf((acc[mi][ni][r] + bv[ni]) * QS);
          }
        }
      }
  }
}

// fused Q + KV projection: 1536 uniform 64x128 jobs, 3 blocks/CU.
// T1 XCD swizzle (bijective): flat -> xcd=flat&7, j=flat>>3, bx=j%24,
// by=xcd*8+j/24. Blocks sharing an A panel (same by) now land on ONE XCD
// (A working set ~3MB fits the 4MB private L2) instead of being sprayed
// across all 8 (8x A re-fetch). Performance-only remap; any XCD mapping
// is correct.
__global__ __launch_bounds__(256, 3) void qkv_k(
    const u16* __restrict__ xb, const u16* __restrict__ yb,
    const u16* __restrict__ Wqt, const u16* __restrict__ Wkvt,
    const float* __restrict__ Wq_b, const float* __restrict__ Wkv_b,
    u16* __restrict__ Qout, u16* __restrict__ KVout)
{
  __shared__ char sA[2 * 8192];
  __shared__ char sB[2 * 16384];
  int flat = (int)blockIdx.x + 24 * (int)blockIdx.y;
  int xcd = flat & 7, j = flat >> 3;
  int bx = j % 24;
  int by = xcd * 8 + j / 24;
  int bm = by * 64;
  if (bx < 16)
    gemm64_body(sA, sB, yb, Wkvt, Wkv_b, (void*)KVout, 2048, 1, bm, bx * 128);
  else
    gemm64_body(sA, sB, xb, Wqt, Wq_b, (void*)Qout, 1024, 0, bm, (bx - 16) * 128);
}

// proj GEMM (epi2, f32 out): grid (8,64) = 512 uniform jobs.
__global__ __launch_bounds__(256, 3) void proj_k(
    const u16* __restrict__ A, const u16* __restrict__ Bt,
    const float* __restrict__ bias, float* __restrict__ fo)
{
  __shared__ char sA[2 * 8192];
  __shared__ char sB[2 * 16384];
  gemm64_body(sA, sB, A, Bt, bias, (void*)fo, 1024, 2,
              blockIdx.y * 64, blockIdx.x * 128);
}

// ---------------- flash attention (verbatim R19/R21 version — passed @42.0us) ------
__global__ __launch_bounds__(512, 2) void attn_k(
    const u16* __restrict__ Qb, const u16* __restrict__ Kb, const u16* __restrict__ Vt,
    const unsigned char* __restrict__ pad, u16* __restrict__ Ob,
    u16* __restrict__ Opart, float* __restrict__ mlbuf)
{
  __shared__ char sK[3][8192];   // [buf][key 0..63][128B row], slot s at phys s^(key&7)
  __shared__ char sV[3][8192];   // [buf][d 0..63][128B row = 64 keys], slot s^(d&7)
  __shared__ char sP[8][2048];   // per-wave P^T: [q15][128B = 64 keys], slot s^(q15&7)
  int t = threadIdx.x, lane = t & 63, w = t >> 6, g = lane >> 4, l15 = lane & 15;
  int x = blockIdx.x, h = blockIdx.y, b = blockIdx.z, bh = b * H_ + h;
  int role = x >> 3, xp = x & 7;
  int qbH = 15 - xp, qbL = xp;
  int nktH = 2 * qbH + 2;        // 18..32
  const int SPLIT = 17;

  const u16* Kbh = Kb + (size_t)bh * L_ * D_;
  const u16* Vbh = Vt + (size_t)bh * D_ * L_;
  const unsigned char* pdb = pad + b * L_;
  int psw = l15 & 7;

  // per-block pad scan (wave-uniform anyp; pad row = 2048B = 128 x 16B)
  const uint4* pp = (const uint4*)pdb;
  uint4 pv0 = pp[lane];
  uint4 pv1 = pp[64 + lane];
  uint32_t nzp = pv0.x | pv0.y | pv0.z | pv0.w | pv1.x | pv1.y | pv1.z | pv1.w;
  bool anyp = __ballot(nzp != 0) != 0;

  // staging (512 threads): 1 K-chunk + 1 V-chunk per thread; chunk t -> row t>>3,
  // 16B slot t&7 (source pre-swizzled, LDS dest linear — T2 both-sides rule)
  int srr = t >> 3, ssp = t & 7;
  int sso = (ssp ^ (srr & 7)) << 4;
#define STAGE(bufi, kt0s) do {                                                        \
    gload16((const char*)(Kbh + (size_t)((kt0s) + srr) * D_) + sso, sK[bufi] + t * 16); \
    gload16((const char*)(Vbh + (size_t)srr * L_ + (kt0s)) + sso, sV[bufi] + t * 16);   \
  } while (0)

  int nphase = role ? 1 : 2;
#pragma unroll 1
  for (int ph = 0; ph < nphase; ph++) {
    int qb, lo, hi, mode;
    if (role) { qb = qbH; lo = 0;     hi = SPLIT;     mode = 1; }  // heavy prefix
    else if (ph == 0) { qb = qbL; lo = 0; hi = 2 * qbL + 2; mode = 0; }  // light full
    else { qb = qbH; lo = SPLIT; hi = nktH; mode = 2; }            // heavy suffix

    int qw0 = qb * 128 + w * 16;
    int bound = qw0 + 15;         // last q-row this wave owns

    // Q fragments: qf[dc] covers d = dc*32 + g*8 .. +7 at q-row qw0 + l15
    const u16* qp = Qb + ((size_t)bh * L_ + qw0 + l15) * D_ + g * 8;
    bf16x8 qf0 = *(const bf16x8*)qp;
    bf16x8 qf1 = *(const bf16x8*)(qp + 32);

    f32x4 zero = {0.f, 0.f, 0.f, 0.f};
    f32x4 oacc[4];
#pragma unroll
    for (int db = 0; db < 4; db++) oacc[db] = zero;
    float mrun = -1e30f, lrun = 0.f;

    if (ph) __syncthreads();      // phase boundary: all waves done with buffers
    STAGE(0, lo << 6);
    int cb = 0, nb = 1;           // compute buf / next (stage) buf, rotate mod 3

#pragma unroll 1
    for (int kt = lo; kt < hi; kt++) {
      int kt0 = kt << 6;
      __builtin_amdgcn_sched_barrier(0);
      if (kt + 1 < hi) {
        STAGE(nb, (kt + 1) << 6);                      // next tile's loads in flight
        asm volatile("s_waitcnt vmcnt(2)" ::: "memory");  // own tile-kt batch landed
      } else {
        asm volatile("s_waitcnt vmcnt(0)" ::: "memory");  // last tile: full drain
      }
      __builtin_amdgcn_s_barrier();                    // all waves' tile-kt loads landed
      __builtin_amdgcn_sched_barrier(0);

      if (kt0 <= bound) {
        // ---- S^T = mfma(K, Q): lane (g,l15) gets keys kb+4g+r at q-col l15 ----
        float sc[4][4];
#pragma unroll
        for (int s = 0; s < 4; s++) {
          int kb = kt0 + s * 16;
          bool live = (kb <= bound);
          f32x4 st = zero;
          uint32_t pb = 0;
          if (live) {
            int R = s * 16 + l15, sw = l15 & 7;
            bf16x8 kf0 = *(const bf16x8*)(sK[cb] + R * 128 + ((g ^ sw) << 4));
            bf16x8 kf1 = *(const bf16x8*)(sK[cb] + R * 128 + (((4 + g) ^ sw) << 4));
            st = MFMA16(kf0, qf0, st);
            st = MFMA16(kf1, qf1, st);
            if (anyp) pb = *(const uint32_t*)(pdb + kb + 4 * g);
          }
          // wave-uniform fast path: sub-tile fully below diagonal and no padding
          bool needm = !live || (kb + 15 > qw0) || anyp;
          if (needm) {
#pragma unroll
            for (int r = 0; r < 4; r++) {
              int key = kb + 4 * g + r;
              bool pm = (pb >> (8 * r)) & 0xffu;
              bool msk = !live || pm || (key > qw0 + l15);
              sc[s][r] = msk ? -1e30f : st[r];
            }
          } else {
#pragma unroll
            for (int r = 0; r < 4; r++) sc[s][r] = st[r];
          }
        }

        // ---- online softmax (T13 defer-rescale, THR=8) + P write ----
        float m0 = fmaxf(fmaxf(sc[0][0], sc[0][1]), fmaxf(sc[0][2], sc[0][3]));
        float m1 = fmaxf(fmaxf(sc[1][0], sc[1][1]), fmaxf(sc[1][2], sc[1][3]));
        float m2 = fmaxf(fmaxf(sc[2][0], sc[2][1]), fmaxf(sc[2][2], sc[2][3]));
        float m3 = fmaxf(fmaxf(sc[3][0], sc[3][1]), fmaxf(sc[3][2], sc[3][3]));
        float mt = fmaxf(fmaxf(m0, m1), fmaxf(m2, m3));
        mt = fmaxf(mt, __shfl_xor(mt, 16));
        mt = fmaxf(mt, __shfl_xor(mt, 32));
        if (!__all(mt <= mrun + 8.0f)) {   // wave-uniform; skip keeps P <= 2^8
          float mnew = fmaxf(mrun, mt);
          float al = __builtin_amdgcn_exp2f(mrun - mnew);
          mrun = mnew;
          lrun *= al;
#pragma unroll
          for (int db = 0; db < 4; db++)
#pragma unroll
            for (int r = 0; r < 4; r++) oacc[db][r] *= al;
        }
        float rs = 0.f;
        char* pwb = sP[w] + l15 * 128 + (g & 1) * 8;
#pragma unroll
        for (int s = 0; s < 4; s++) {
          float p0 = __builtin_amdgcn_exp2f(sc[s][0] - mrun);
          float p1 = __builtin_amdgcn_exp2f(sc[s][1] - mrun);
          float p2 = __builtin_amdgcn_exp2f(sc[s][2] - mrun);
          float p3 = __builtin_amdgcn_exp2f(sc[s][3] - mrun);
          rs += (p0 + p1) + (p2 + p3);
          uint32_t w0 = cvt_pk_bf16(p0, p1), w1 = cvt_pk_bf16(p2, p3);
          char* dst = pwb + (((2 * s + (g >> 1)) ^ psw) << 4);
          *(uint32_t*)dst = w0;
          *(uint32_t*)(dst + 4) = w1;
        }
        rs += __shfl_xor(rs, 16);
        rs += __shfl_xor(rs, 32);
        lrun += rs;

        // ---- PV: O^T += V^T . P^T ----
#pragma unroll
        for (int kc = 0; kc < 2; kc++) {
          if (kt0 + 32 * kc <= bound) {
            bf16x8 pf = *(const bf16x8*)(sP[w] + l15 * 128 + (((4 * kc + g) ^ psw) << 4));
#pragma unroll
            for (int db = 0; db < 4; db++) {
              int dR = db * 16 + l15;
              bf16x8 vf = *(const bf16x8*)(sV[cb] + dR * 128 +
                                           (((4 * kc + g) ^ (dR & 7)) << 4));
              oacc[db] = MFMA16(vf, pf, oacc[db]);
            }
          }
        }
      }
      cb = (cb == 2) ? 0 : cb + 1;
      nb = (nb == 2) ? 0 : nb + 1;
    }

    // epilogue: lane holds O^T[d = db*16 + g*4 + r][q = qw0 + l15]
    float rl = (lrun != 0.f) ? 1.0f / lrun : 0.f;   // suffix waves may have no tiles
    int q = qw0 + l15;
    if (mode == 0) {
      u16* op = Ob + ((size_t)b * L_ + q) * HD_ + h * D_ + g * 4;
#pragma unroll
      for (int db = 0; db < 4; db++) {
        ushort4 pk;
        pk.x = f2bf(oacc[db][0] * rl);
        pk.y = f2bf(oacc[db][1] * rl);
        pk.z = f2bf(oacc[db][2] * rl);
        pk.w = f2bf(oacc[db][3] * rl);
        *(ushort4*)(op + db * 16) = pk;
      }
    } else {
      int part = mode - 1;
      size_t prow = (size_t)part * 32768 + (size_t)bh * 1024 + (q - 1024);
      u16* op = Opart + prow * 64 + g * 4;
#pragma unroll
      for (int db = 0; db < 4; db++) {
        ushort4 pk;
        pk.x = f2bf(oacc[db][0] * rl);
        pk.y = f2bf(oacc[db][1] * rl);
        pk.z = f2bf(oacc[db][2] * rl);
        pk.w = f2bf(oacc[db][3] * rl);
        *(ushort4*)(op + db * 16) = pk;
      }
      if (g == 0) {
        mlbuf[prow * 2]     = mrun;   // log2-domain running max
        mlbuf[prow * 2 + 1] = lrun;
      }
    }
  }
#undef STAGE
}

// ---------------- merge of split-KV partials (rows 1024..2047 of each b) --------
__global__ __launch_bounds__(256) void merge_k(
    const u16* __restrict__ Op, const float* __restrict__ ml, u16* __restrict__ Ob)
{
  int tid = blockIdx.x * 256 + threadIdx.x;   // 262144 total
  int d0 = (tid & 7) * 8;
  int row = tid >> 3;                          // bh*1024 + qrel  (32768 rows)
  int qrel = row & 1023, bh = row >> 10;
  int b = bh >> 4, h = bh & 15;
  float m0 = ml[(size_t)row * 2],            l0 = ml[(size_t)row * 2 + 1];
  float m1 = ml[((size_t)32768 + row) * 2],  l1 = ml[((size_t)32768 + row) * 2 + 1];
  float M = fmaxf(m0, m1);
  float w0 = l0 * __builtin_amdgcn_exp2f(m0 - M);
  float w1 = l1 * __builtin_amdgcn_exp2f(m1 - M);
  float rw = 1.0f / (w0 + w1);
  w0 *= rw; w1 *= rw;
  bf16x8 a = *(const bf16x8*)(Op + (size_t)row * 64 + d0);
  bf16x8 c = *(const bf16x8*)(Op + ((size_t)32768 + row) * 64 + d0);
  bf16x8 o;
#pragma unroll
  for (int j = 0; j < 8; j++)
    o[j] = (short)f2bf(w0 * bf2f((u16)a[j]) + w1 * bf2f((u16)c[j]));
  *(bf16x8*)(Ob + ((size_t)b * L_ + 1024 + qrel) * HD_ + h * D_ + d0) = o;
}

extern "C" void kernel_launch(void* const* d_in, const int* in_sizes, int n_in,
                              void* d_out, int out_size, void* d_ws, size_t ws_size,
                              hipStream_t stream) {
  const float* x      = (const float*)d_in[0];
  const float* y      = (const float*)d_in[1];
  const unsigned char* mask = (const unsigned char*)d_in[2];
  const float* Wq_w   = (const float*)d_in[3];
  const float* Wq_b   = (const float*)d_in[4];
  const float* Wkv_w  = (const float*)d_in[5];
  const float* Wkv_b  = (const float*)d_in[6];
  const float* proj_w = (const float*)d_in[7];
  const float* proj_b = (const float*)d_in[8];

  char* ws = (char*)d_ws;
  u16* xb   = (u16*)(ws);                        // 8 MB  (reused as Ob after qkv)
  u16* yb   = (u16*)(ws + (size_t)(8  << 20));   // 8 MB  (reused as Opart after qkv)
  u16* Wqt  = (u16*)(ws + (size_t)(16 << 20));   // 2 MB  (reused as mlbuf after qkv)
  u16* Wkvt = (u16*)(ws + (size_t)(18 << 20));   // 4 MB
  u16* Wpt  = (u16*)(ws + (size_t)(22 << 20));   // 2 MB  (live until proj!)
  u16* Qb   = (u16*)(ws + (size_t)(24 << 20));   // 8 MB
  u16* Kb   = (u16*)(ws + (size_t)(32 << 20));   // 8 MB (V^T follows contiguously)
  u16* Vtb  = (u16*)(ws + (size_t)(40 << 20));   // 8 MB, layout [b,h,d,l]
  u16* Ob   = xb;
  u16* Opart  = yb;                              // dead after qkv; 8 MB exact
  float* mlbuf = (float*)Wqt;                    // dead after qkv; 512 KB of 2 MB

  hipLaunchKernelGGL(prologue_k, dim3(5120), dim3(256), 0, stream,
                     x, y, xb, yb, Wq_w, Wkv_w, proj_w, Wqt, Wkvt, Wpt);
  // fused: Q = (xb@Wq+b)*SCL -> [b,h,l,d]; KV = yb@Wkv+b -> K [b,h,l,d], V^T [b,h,d,l]
  hipLaunchKernelGGL(qkv_k, dim3(24, 64), dim3(256), 0, stream,
                     xb, yb, Wqt, Wkvt, Wq_b, Wkv_b, Qb, Kb);
  hipLaunchKernelGGL(attn_k, dim3(16, H_, B_), dim3(512), 0, stream,
                     Qb, Kb, Vtb, mask, Ob, Opart, mlbuf);
  hipLaunchKernelGGL(merge_k, dim3(1024), dim3(256), 0, stream, Opart, mlbuf, Ob);
  // out = Ob @ proj + b -> f32
  hipLaunchKernelGGL(proj_k, dim3(8, 64), dim3(256), 0, stream, Ob, Wpt, proj_b, (float*)d_out);
}